// Round 1
// baseline (134.469 us; speedup 1.0000x reference)
//
#include <hip/hip_runtime.h>
#include <stdint.h>

// HierarchicalZ2_12Quantizer on MI355X (gfx950)
// tokens = 8*4096 = 32768, D = 1024
// down-proj (x @ [w_gate|w_to_l1|w_to_l2|w_to_l3u|w_to_l3l]) via bf16 MFMA,
// per-thread soft-quantize (codes derived from bit patterns: hypercube order
// of itertools.product([-1,1], repeat=n): c[j][i] = ((j>>(n-1-i))&1)?+1:-1),
// up-proj (V @ [w_from_l1|w_from_l2|w_from_l3]) via single-K-step bf16 MFMA.

#define DM 1024
#define MT 128
#define OUT_OFF ((size_t)33554432)  // 8*4096*1024

typedef float f32x4 __attribute__((ext_vector_type(4)));
typedef short bf16x8 __attribute__((ext_vector_type(8)));

__device__ __forceinline__ short f2bf(float f){
  unsigned u = __builtin_bit_cast(unsigned, f);
  unsigned r = u + 0x7fffu + ((u >> 16) & 1u);   // round-to-nearest-even
  return (short)(r >> 16);
}

// soft_quantize over the 2^NB hypercube corners; z[NB] -> q[NB]
template<int NB>
__device__ __forceinline__ void softq(const float* z, float invt, float* q){
  constexpr int K = 1 << NB;
  float d[K];
  float dmin = 3.4e38f;
#pragma unroll
  for (int j = 0; j < K; ++j){
    float acc = 0.f;
#pragma unroll
    for (int i = 0; i < NB; ++i){
      float c = ((j >> (NB-1-i)) & 1) ? 1.f : -1.f;
      float t = z[i] - c;
      acc = fmaf(t, t, acc);
    }
    float dj = sqrtf(acc);
    d[j] = dj;
    dmin = fminf(dmin, dj);
  }
  float S = 0.f;
  float s1[NB];
#pragma unroll
  for (int i = 0; i < NB; ++i) s1[i] = 0.f;
#pragma unroll
  for (int j = 0; j < K; ++j){
    float wj = __expf((dmin - d[j]) * invt);
    S += wj;
#pragma unroll
    for (int i = 0; i < NB; ++i)
      if ((j >> (NB-1-i)) & 1) s1[i] += wj;   // compile-time bit -> no branch
  }
  float rS = 1.f / S;
#pragma unroll
  for (int i = 0; i < NB; ++i) q[i] = 2.f * s1[i] * rS - 1.f;  // (S1-S0)/S
}

__global__ __launch_bounds__(512) void hq_kernel(
    const float* __restrict__ x,
    const float* __restrict__ w_to_l1,  const float* __restrict__ w_from_l1,
    const float* __restrict__ w_to_l2,  const float* __restrict__ w_from_l2,
    const float* __restrict__ w_to_l3u, const float* __restrict__ w_to_l3l,
    const float* __restrict__ w_from_l3,const float* __restrict__ w_gate,
    const float* __restrict__ b_gate,
    const float* __restrict__ t1p, const float* __restrict__ t2p, const float* __restrict__ t3p,
    const float* __restrict__ s1p, const float* __restrict__ s2p, const float* __restrict__ s3p,
    float* __restrict__ out)
{
  // WF holds, in sequence, the fragment-packed down-proj B (32 ksteps x 2 nfrags)
  // and later the fragment-packed up-proj B (64 dfrags). 64 KB, reused.
  __shared__ alignas(16) short WF[32768];
  __shared__ float P [MT*33];   // down-proj result, padded rows (bank-conflict-free)
  __shared__ float V [MT*25];   // up-proj A operand (cols 21..24 zero)
  __shared__ float GS[MT*3];    // gate * scale per token

  const int tid  = threadIdx.x;
  const int l    = tid & 63;
  const int wv   = tid >> 6;    // wave 0..7, owns tokens [16*wv, 16*wv+16)
  const int kg   = l >> 4;      // k-group 0..3
  const int ln16 = l & 15;
  const int tb   = blockIdx.x * MT;

  // ---- stage W24 B-fragments: frag layout B[k][n], lane: n=nf*16+(l&15), k=32s+kg*8+j
  for (int e = tid; e < 32768; e += 512){
    int s  = e >> 10;
    int nf = (e >> 9) & 1;
    int ll = (e >> 3) & 63;
    int j  = e & 7;
    int k  = s*32 + ((ll >> 4) << 3) + j;
    int n  = nf*16 + (ll & 15);
    float v;
    if      (n < 3)  v = w_gate  [k*3 + n];
    else if (n < 6)  v = w_to_l1 [k*3 + (n-3)];
    else if (n < 12) v = w_to_l2 [k*6 + (n-6)];
    else if (n < 18) v = w_to_l3u[k*6 + (n-12)];
    else if (n < 24) v = w_to_l3l[k*6 + (n-18)];
    else             v = 0.f;
    WF[e] = f2bf(v);
  }
  __syncthreads();

  // ---- down-proj: P[tok][0:24] = x @ W24  (cols: gate0..2, z1 x3, z2 x6, z3u x6, z3l x6)
  {
    f32x4 acc0 = {0.f,0.f,0.f,0.f}, acc1 = {0.f,0.f,0.f,0.f};
    const float* xrow = x + (size_t)(tb + wv*16 + ln16)*DM + kg*8;
#pragma unroll 4
    for (int s = 0; s < 32; ++s){
      const float4* xp = reinterpret_cast<const float4*>(xrow + s*32);
      float4 a0 = xp[0];
      float4 a1 = xp[1];
      bf16x8 af;
      af[0]=f2bf(a0.x); af[1]=f2bf(a0.y); af[2]=f2bf(a0.z); af[3]=f2bf(a0.w);
      af[4]=f2bf(a1.x); af[5]=f2bf(a1.y); af[6]=f2bf(a1.z); af[7]=f2bf(a1.w);
      bf16x8 b0 = *reinterpret_cast<const bf16x8*>(&WF[(s*2+0)*512 + l*8]);
      bf16x8 b1 = *reinterpret_cast<const bf16x8*>(&WF[(s*2+1)*512 + l*8]);
      acc0 = __builtin_amdgcn_mfma_f32_16x16x32_bf16(af, b0, acc0, 0, 0, 0);
      acc1 = __builtin_amdgcn_mfma_f32_16x16x32_bf16(af, b1, acc1, 0, 0, 0);
    }
#pragma unroll
    for (int r = 0; r < 4; ++r){        // D: col = l&15, row = kg*4 + r
      int lr = wv*16 + kg*4 + r;
      P[lr*33 + ln16]      = acc0[r];
      P[lr*33 + 16 + ln16] = acc1[r];
    }
  }
  __syncthreads();

  // ---- stage Wf B-fragments (overwrite WF): B[k][d], k 0..20 real, 21..31 zero
  for (int e = tid; e < 32768; e += 512){
    int f  = e >> 9;
    int ll = (e >> 3) & 63;
    int j  = e & 7;
    int k  = ((ll >> 4) << 3) + j;
    int dd = f*16 + (ll & 15);
    float v;
    if      (k < 3)  v = w_from_l1[k*DM + dd];
    else if (k < 9)  v = w_from_l2[(k-3)*DM + dd];
    else if (k < 21) v = w_from_l3[(k-9)*DM + dd];
    else             v = 0.f;
    WF[e] = f2bf(v);
  }

  // ---- quantize: one token per thread, 4 role groups of 128 threads
  {
    const int grp = tid >> 7;   // 0:l2  1:l3u  2:l3l  3:gate+l1
    const int t   = tid & 127;
    float qv[6] = {0,0,0,0,0,0};
    float myscale = 0.f;
    if (grp == 3){
      float invt1 = 1.f / fminf(fmaxf(__expf(t1p[0]), 0.01f), 5.0f);
      float g0l = P[t*33+0] + b_gate[0];
      float g1l = P[t*33+1] + b_gate[1];
      float g2l = P[t*33+2] + b_gate[2];
      float m  = fmaxf(g0l, fmaxf(g1l, g2l));
      float e0 = __expf(g0l - m), e1 = __expf(g1l - m), e2 = __expf(g2l - m);
      float rs = 1.f / (e0 + e1 + e2);
      float g0 = e0*rs, g1 = e1*rs, g2 = e2*rs;
      GS[t*3+0] = g0 * s1p[0];
      GS[t*3+1] = g1 * s2p[0];
      GS[t*3+2] = g2 * s3p[0];
      myscale   = g0 * s1p[0];
      float z1[3] = {P[t*33+3], P[t*33+4], P[t*33+5]};
      softq<3>(z1, invt1, qv);
      // gate means: wave reduce + atomic (zeroed by zero_gate_kernel each launch)
      float sg0=g0, sg1=g1, sg2=g2;
#pragma unroll
      for (int mm = 1; mm < 64; mm <<= 1){
        sg0 += __shfl_xor(sg0, mm, 64);
        sg1 += __shfl_xor(sg1, mm, 64);
        sg2 += __shfl_xor(sg2, mm, 64);
      }
      if (l == 0){
        const float sc = 1.f / 32768.f;
        atomicAdd(out + OUT_OFF + 0, sg0 * sc);
        atomicAdd(out + OUT_OFF + 1, sg1 * sc);
        atomicAdd(out + OUT_OFF + 2, sg2 * sc);
      }
    } else {
      float tl = (grp == 0) ? t2p[0] : t3p[0];
      float invt = 1.f / fminf(fmaxf(__expf(tl), 0.01f), 5.0f);
      float z[6];
#pragma unroll
      for (int i = 0; i < 6; ++i) z[i] = P[t*33 + 6 + grp*6 + i];
      softq<6>(z, invt, qv);
    }
    __syncthreads();   // GS visible; uniform barrier
    if (grp == 3){
#pragma unroll
      for (int i = 0; i < 3; ++i) V[t*25 + i] = myscale * qv[i];
#pragma unroll
      for (int i = 21; i < 25; ++i) V[t*25 + i] = 0.f;
    } else {
      float sc = GS[t*3 + ((grp == 0) ? 1 : 2)];
      int voff = 3 + grp*6;   // l2 -> 3..8, l3u -> 9..14, l3l -> 15..20
#pragma unroll
      for (int i = 0; i < 6; ++i) V[t*25 + voff + i] = sc * qv[i];
    }
  }
  __syncthreads();

  // ---- up-proj + epilogue: out = x + V @ Wf
  {
    bf16x8 aV = {0,0,0,0,0,0,0,0};
    if (kg < 3){   // k 24..31 are structurally zero
      const float* vp = &V[(wv*16 + ln16)*25 + kg*8];
#pragma unroll
      for (int j = 0; j < 8; ++j) aV[j] = f2bf(vp[j]);
    }
    const f32x4 zero4 = {0.f,0.f,0.f,0.f};
    const size_t rowbase = (size_t)(tb + wv*16 + kg*4)*DM;
#pragma unroll 4
    for (int f = 0; f < 64; ++f){
      bf16x8 bfr = *reinterpret_cast<const bf16x8*>(&WF[f*512 + l*8]);
      f32x4 dd = __builtin_amdgcn_mfma_f32_16x16x32_bf16(aV, bfr, zero4, 0, 0, 0);
      const int col = f*16 + ln16;
#pragma unroll
      for (int r = 0; r < 4; ++r){
        size_t idx = rowbase + (size_t)r*DM + col;
        out[idx] = x[idx] + dd[r];
      }
    }
  }
}

__global__ void zero_gate_kernel(float* out){
  if (threadIdx.x < 3) out[OUT_OFF + threadIdx.x] = 0.f;
}

extern "C" void kernel_launch(void* const* d_in, const int* in_sizes, int n_in,
                              void* d_out, int out_size, void* d_ws, size_t ws_size,
                              hipStream_t stream){
  (void)in_sizes; (void)n_in; (void)d_ws; (void)ws_size; (void)out_size;
  const float* x         = (const float*)d_in[0];
  // d_in[1] (codes_l1), d_in[2] (codes_l2) unused: corners derived from bits
  const float* w_to_l1   = (const float*)d_in[3];
  const float* w_from_l1 = (const float*)d_in[4];
  const float* w_to_l2   = (const float*)d_in[5];
  const float* w_from_l2 = (const float*)d_in[6];
  const float* w_to_l3u  = (const float*)d_in[7];
  const float* w_to_l3l  = (const float*)d_in[8];
  const float* w_from_l3 = (const float*)d_in[9];
  const float* w_gate    = (const float*)d_in[10];
  const float* b_gate    = (const float*)d_in[11];
  const float* t1 = (const float*)d_in[12];
  const float* t2 = (const float*)d_in[13];
  const float* t3 = (const float*)d_in[14];
  const float* s1 = (const float*)d_in[15];
  const float* s2 = (const float*)d_in[16];
  const float* s3 = (const float*)d_in[17];
  float* out = (float*)d_out;

  zero_gate_kernel<<<dim3(1), dim3(64), 0, stream>>>(out);
  hq_kernel<<<dim3(256), dim3(512), 0, stream>>>(
      x, w_to_l1, w_from_l1, w_to_l2, w_from_l2, w_to_l3u, w_to_l3l,
      w_from_l3, w_gate, b_gate, t1, t2, t3, s1, s2, s3, out);
}